// Round 4
// baseline (601.866 us; speedup 1.0000x reference)
//
#include <hip/hip_runtime.h>

#define N_NODES 50000
#define N_EDGES 800000
#define FEAT    16
#define HID     128
#define NLAYERS 4
#define OUTD    12
#define NGRAPH  1024
#define SCAN_NB 196   // ceil((N_NODES+1)/256)

__device__ inline float4 f4zero() { return make_float4(0.f, 0.f, 0.f, 0.f); }
__device__ inline float4 f4fma(float a, float4 w, float4 acc) {
    acc.x = fmaf(a, w.x, acc.x);
    acc.y = fmaf(a, w.y, acc.y);
    acc.z = fmaf(a, w.z, acc.z);
    acc.w = fmaf(a, w.w, acc.w);
    return acc;
}
__device__ inline float4 f4add(float4 a, float4 b) {
    return make_float4(a.x + b.x, a.y + b.y, a.z + b.z, a.w + b.w);
}
__device__ inline float4 f4relu(float4 a) {
    return make_float4(fmaxf(a.x, 0.f), fmaxf(a.y, 0.f), fmaxf(a.z, 0.f), fmaxf(a.w, 0.f));
}

// ---------------- degree / dinv ----------------
__global__ void k_deg(const int* __restrict__ ei, int* __restrict__ degi) {
    int e = blockIdx.x * 256 + threadIdx.x;
    if (e < N_EDGES) atomicAdd(&degi[ei[N_EDGES + e]], 1);
}

__global__ void k_dinv(const int* __restrict__ degi, float* __restrict__ dinv) {
    int i = blockIdx.x * 256 + threadIdx.x;
    if (i < N_NODES) dinv[i] = rsqrtf((float)degi[i] + 1.0f);
}

// ---------------- 3-kernel exclusive scan over deg (N_NODES+1 elems) ----------------
__global__ void k_scan_part(const int* __restrict__ degi, int* __restrict__ part) {
    __shared__ int s[256];
    int t = threadIdx.x;
    int i = blockIdx.x * 256 + t;
    int v = (i < N_NODES) ? degi[i] : 0;
    s[t] = v;
    __syncthreads();
    for (int st = 128; st > 0; st >>= 1) {
        if (t < st) s[t] += s[t + st];
        __syncthreads();
    }
    if (t == 0) part[blockIdx.x] = s[0];
}

__global__ void k_scan_mid(int* __restrict__ part) {
    __shared__ int s[256];
    int t = threadIdx.x;
    int v = (t < SCAN_NB) ? part[t] : 0;
    s[t] = v;
    __syncthreads();
    for (int st = 1; st < 256; st <<= 1) {
        int u = (t >= st) ? s[t - st] : 0;
        __syncthreads();
        s[t] += u;
        __syncthreads();
    }
    if (t < SCAN_NB) part[t] = s[t] - v;   // exclusive
}

__global__ void k_scan_final(const int* __restrict__ degi, const int* __restrict__ part,
                             int* __restrict__ offs) {
    __shared__ int s[256];
    int t = threadIdx.x;
    int i = blockIdx.x * 256 + t;
    int v = (i < N_NODES) ? degi[i] : 0;
    s[t] = v;
    __syncthreads();
    for (int st = 1; st < 256; st <<= 1) {
        int u = (t >= st) ? s[t - st] : 0;
        __syncthreads();
        s[t] += u;
        __syncthreads();
    }
    if (i <= N_NODES) offs[i] = s[t] - v + part[blockIdx.x];
}

// ---------------- CSR fill: packed record {src, dinv[src]} ----------------
__global__ void k_fill(const int* __restrict__ ei, const int* __restrict__ offs,
                       const float* __restrict__ dinv,
                       int* __restrict__ cursor, int2* __restrict__ erec) {
    int e = blockIdx.x * 256 + threadIdx.x;
    if (e < N_EDGES) {
        int srcv = ei[e];
        int dstv = ei[N_EDGES + e];
        int p = atomicAdd(&cursor[dstv], 1);
        erec[offs[dstv] + p] = make_int2(srcv, __float_as_int(dinv[srcv]));
    }
}

// ---------------- fused node-embed MLP: hA = relu(x@We1+be1)@We2+be2 ----------------
#define GM 64
__global__ void __launch_bounds__(256) k_embed_fused(
        const float* __restrict__ x,
        const float* __restrict__ W1, const float* __restrict__ b1,
        const float* __restrict__ W2, const float* __restrict__ b2,
        float* __restrict__ outp) {
    __shared__ float x_l[GM][FEAT];
    __shared__ float a_l[GM][HID];
    int t = threadIdx.x;
    long n0 = (long)blockIdx.x * GM;
    // coop load 64x16 floats = 256 float4, 1/thread
    {
        int r  = t >> 2;
        int c4 = (t & 3) << 2;
        long n = n0 + r;
        float4 v = (n < N_NODES) ? *(const float4*)&x[n * FEAT + c4] : f4zero();
        *(float4*)&x_l[r][c4] = v;
    }
    __syncthreads();
    int fgrp = t & 31, ngrp = t >> 5;
    int f4 = fgrp << 2;
    // stage 1: t = relu(x@W1+b1), K=16
    {
        float4 acc[8];
#pragma unroll
        for (int r = 0; r < 8; ++r) acc[r] = f4zero();
#pragma unroll
        for (int k4 = 0; k4 < 4; ++k4) {
            float4 wv[4];
#pragma unroll
            for (int kk = 0; kk < 4; ++kk)
                wv[kk] = *(const float4*)&W1[(k4 * 4 + kk) * HID + f4];
            float4 xv[8];
#pragma unroll
            for (int r = 0; r < 8; ++r)
                xv[r] = *(const float4*)&x_l[ngrp * 8 + r][k4 << 2];
#pragma unroll
            for (int r = 0; r < 8; ++r) {
                acc[r] = f4fma(xv[r].x, wv[0], acc[r]);
                acc[r] = f4fma(xv[r].y, wv[1], acc[r]);
                acc[r] = f4fma(xv[r].z, wv[2], acc[r]);
                acc[r] = f4fma(xv[r].w, wv[3], acc[r]);
            }
        }
        float4 bv = *(const float4*)&b1[f4];
#pragma unroll
        for (int r = 0; r < 8; ++r)
            *(float4*)&a_l[ngrp * 8 + r][f4] = f4relu(f4add(acc[r], bv));
    }
    __syncthreads();
    // stage 2: out = t @ W2 + b2, K=128
    float4 acc[8];
#pragma unroll
    for (int r = 0; r < 8; ++r) acc[r] = f4zero();
#pragma unroll 4
    for (int k4 = 0; k4 < 32; ++k4) {
        float4 wv[4];
#pragma unroll
        for (int kk = 0; kk < 4; ++kk)
            wv[kk] = *(const float4*)&W2[(k4 * 4 + kk) * HID + f4];
        float4 av[8];
#pragma unroll
        for (int r = 0; r < 8; ++r)
            av[r] = *(const float4*)&a_l[ngrp * 8 + r][k4 << 2];
#pragma unroll
        for (int r = 0; r < 8; ++r) {
            acc[r] = f4fma(av[r].x, wv[0], acc[r]);
            acc[r] = f4fma(av[r].y, wv[1], acc[r]);
            acc[r] = f4fma(av[r].z, wv[2], acc[r]);
            acc[r] = f4fma(av[r].w, wv[3], acc[r]);
        }
    }
    float4 bv = *(const float4*)&b2[f4];
#pragma unroll
    for (int r = 0; r < 8; ++r) {
        long n = n0 + ngrp * 8 + r;
        if (n < N_NODES) *(float4*)&outp[n * HID + f4] = f4add(acc[r], bv);
    }
}

// ---------------- dense GEMM: B = A @ W, A [N,128], W [128,128] ----------------
// M=64 nodes/block, 256 threads, 8 nodes/thread, k-unroll 4 via ds_read_b128.
__global__ void __launch_bounds__(256) k_gemm(
        const float* __restrict__ A, const float* __restrict__ W,
        float* __restrict__ B) {
    __shared__ float a_l[GM][HID];
    int t = threadIdx.x;
    long n0 = (long)blockIdx.x * GM;
#pragma unroll
    for (int i = 0; i < 8; ++i) {
        int p  = t + 256 * i;
        int r  = p >> 5;
        int c4 = (p & 31) << 2;
        long n = n0 + r;
        float4 v = (n < N_NODES) ? *(const float4*)&A[n * HID + c4] : f4zero();
        *(float4*)&a_l[r][c4] = v;
    }
    __syncthreads();
    int fgrp = t & 31, ngrp = t >> 5;
    int f4 = fgrp << 2;
    float4 acc[8];
#pragma unroll
    for (int r = 0; r < 8; ++r) acc[r] = f4zero();
#pragma unroll 4
    for (int k4 = 0; k4 < 32; ++k4) {
        float4 wv[4];
#pragma unroll
        for (int kk = 0; kk < 4; ++kk)
            wv[kk] = *(const float4*)&W[(k4 * 4 + kk) * HID + f4];
        float4 av[8];
#pragma unroll
        for (int r = 0; r < 8; ++r)
            av[r] = *(const float4*)&a_l[ngrp * 8 + r][k4 << 2];
#pragma unroll
        for (int r = 0; r < 8; ++r) {
            acc[r] = f4fma(av[r].x, wv[0], acc[r]);
            acc[r] = f4fma(av[r].y, wv[1], acc[r]);
            acc[r] = f4fma(av[r].z, wv[2], acc[r]);
            acc[r] = f4fma(av[r].w, wv[3], acc[r]);
        }
    }
#pragma unroll
    for (int r = 0; r < 8; ++r) {
        long n = n0 + ngrp * 8 + r;
        if (n < N_NODES) *(float4*)&B[n * HID + f4] = acc[r];
    }
}

// ---------------- CSR aggregation + self-loop + bias + relu ----------------
// One wave per dst node; lane owns 2 features (float2); 16 gathers in flight.
__global__ void __launch_bounds__(256) k_agg(
        const float* __restrict__ hp,       // h' = h @ W
        const int2* __restrict__ erec, const int* __restrict__ offs,
        const float* __restrict__ dinv, const float* __restrict__ bias,
        float* __restrict__ hout) {
    int t = threadIdx.x;
    int lane = t & 63;
    int w = t >> 6;                       // wave 0..3
    int i = blockIdx.x * 4 + w;
    if (i >= N_NODES) return;
    float di = dinv[i];
    int s0 = offs[i], s1 = offs[i + 1];
    const float2* hp2 = (const float2*)hp;
    float2 self = hp2[(long)i * 64 + lane];
    float2 bv = ((const float2*)bias)[lane];
    float ax = fmaf(di * di, self.x, bv.x);
    float ay = fmaf(di * di, self.y, bv.y);
    for (int base = s0; base < s1; base += 64) {
        int n = s1 - base; if (n > 64) n = 64;
        int last = n - 1;
        int2 e = (lane < n) ? erec[base + lane] : make_int2(0, 0);
        int   sv_l = e.x;
        float nm_l = __int_as_float(e.y);
        for (int k = 0; k < n; k += 16) {
            int a[16]; float m[16];
#pragma unroll
            for (int u = 0; u < 16; ++u) {
                int kk = k + u;
                int ks = kk < last ? kk : last;   // clamp to last real edge
                a[u] = __shfl(sv_l, ks);
                float mu = __shfl(nm_l, ks);
                m[u] = (kk < n) ? mu * di : 0.f;
            }
            float2 v[16];
#pragma unroll
            for (int u = 0; u < 16; ++u) v[u] = hp2[(long)a[u] * 64 + lane];
#pragma unroll
            for (int u = 0; u < 16; ++u) {
                ax = fmaf(m[u], v[u].x, ax);
                ay = fmaf(m[u], v[u].y, ay);
            }
        }
    }
    float2 r;
    r.x = fmaxf(ax, 0.f);
    r.y = fmaxf(ay, 0.f);
    ((float2*)hout)[(long)i * 64 + lane] = r;
}

// ---------------- pooling: sorted-batch run-length accumulation ----------------
#define PN 16
__global__ void __launch_bounds__(256) k_pool(
        const float* __restrict__ h, const int* __restrict__ batch,
        float* __restrict__ pooled, float* __restrict__ cnt) {
    int t = threadIdx.x;
    int lane = t & 31, grp = t >> 5;
    long n0 = ((long)blockIdx.x * 8 + grp) * PN;
    if (n0 >= N_NODES) return;
    long n1 = n0 + PN; if (n1 > N_NODES) n1 = N_NODES;
    const float4* h4 = (const float4*)h;
    float4 run = f4zero();
    int curg = batch[n0];
    int c = 0;
    for (long n = n0; n < n1; ++n) {
        int g = batch[n];
        if (g != curg) {
            float* pb = &pooled[(long)curg * HID + (lane << 2)];
            atomicAdd(pb + 0, run.x); atomicAdd(pb + 1, run.y);
            atomicAdd(pb + 2, run.z); atomicAdd(pb + 3, run.w);
            if (lane == 0) atomicAdd(&cnt[curg], (float)c);
            run = f4zero(); c = 0; curg = g;
        }
        run = f4add(run, h4[n * 32 + lane]);
        ++c;
    }
    float* pb = &pooled[(long)curg * HID + (lane << 2)];
    atomicAdd(pb + 0, run.x); atomicAdd(pb + 1, run.y);
    atomicAdd(pb + 2, run.z); atomicAdd(pb + 3, run.w);
    if (lane == 0) atomicAdd(&cnt[curg], (float)c);
}

// ---------------- output head: out = (pooled/cnt) @ Wo + bo ----------------
__global__ void __launch_bounds__(HID) k_out(
        const float* __restrict__ pooled, const float* __restrict__ cnt,
        const float* __restrict__ Wo, const float* __restrict__ bo,
        float* __restrict__ out) {
    __shared__ float p[HID];
    int g = blockIdx.x;
    int f = threadIdx.x;
    float inv = 1.0f / fmaxf(cnt[g], 1.0f);
    p[f] = pooled[g * HID + f] * inv;
    __syncthreads();
    if (f < OUTD) {
        float acc = bo[f];
#pragma unroll 8
        for (int k = 0; k < HID; ++k) acc += p[k] * Wo[k * OUTD + f];
        out[g * OUTD + f] = acc;
    }
}

extern "C" void kernel_launch(void* const* d_in, const int* in_sizes, int n_in,
                              void* d_out, int out_size, void* d_ws, size_t ws_size,
                              hipStream_t stream) {
    const float* x    = (const float*)d_in[0];
    const int*   ei   = (const int*)d_in[1];
    // d_in[2] edge_attr unused
    const int*   bidx = (const int*)d_in[3];
    const float* We1  = (const float*)d_in[4];
    const float* be1  = (const float*)d_in[5];
    const float* We2  = (const float*)d_in[6];
    const float* be2  = (const float*)d_in[7];
    const float* Wg   = (const float*)d_in[8];
    const float* bg   = (const float*)d_in[9];
    const float* Wo   = (const float*)d_in[10];
    const float* bo   = (const float*)d_in[11];
    float* out = (float*)d_out;

    // ---- workspace layout (256B aligned) ----
    char* ws = (char*)d_ws;
    size_t o = 0;
    auto take = [&](size_t bytes) { size_t r = o; o += (bytes + 255) & ~(size_t)255; return r; };
    size_t off_degi   = take((size_t)N_NODES * 4);
    size_t off_cursor = take((size_t)N_NODES * 4);
    size_t off_pooled = take((size_t)NGRAPH * HID * 4);
    size_t off_cnt    = take((size_t)NGRAPH * 4);
    size_t zero_bytes = o;                       // [0, o) gets memset to 0
    size_t off_dinv   = take((size_t)N_NODES * 4);
    size_t off_offs   = take((size_t)(N_NODES + 1) * 4);
    size_t off_part   = take((size_t)256 * 4);
    size_t off_erec   = take((size_t)N_EDGES * 8);
    size_t off_hA     = take((size_t)N_NODES * HID * 4);
    size_t off_hB     = take((size_t)N_NODES * HID * 4);

    int*   degi   = (int*)(ws + off_degi);
    int*   cursor = (int*)(ws + off_cursor);
    float* pooled = (float*)(ws + off_pooled);
    float* cnt    = (float*)(ws + off_cnt);
    float* dinv   = (float*)(ws + off_dinv);
    int*   offs   = (int*)(ws + off_offs);
    int*   part   = (int*)(ws + off_part);
    int2*  erec   = (int2*)(ws + off_erec);
    float* hA     = (float*)(ws + off_hA);
    float* hB     = (float*)(ws + off_hB);

    hipMemsetAsync(d_ws, 0, zero_bytes, stream);

    // degree + dinv + CSR build (amortized across 4 layers)
    k_deg<<<(N_EDGES + 255) / 256, 256, 0, stream>>>(ei, degi);
    k_dinv<<<(N_NODES + 255) / 256, 256, 0, stream>>>(degi, dinv);
    k_scan_part<<<SCAN_NB, 256, 0, stream>>>(degi, part);
    k_scan_mid<<<1, 256, 0, stream>>>(part);
    k_scan_final<<<SCAN_NB, 256, 0, stream>>>(degi, part, offs);
    k_fill<<<(N_EDGES + 255) / 256, 256, 0, stream>>>(ei, offs, dinv, cursor, erec);

    // fused node-embed MLP
    int gemm_grid = (N_NODES + GM - 1) / GM;
    k_embed_fused<<<gemm_grid, 256, 0, stream>>>(x, We1, be1, We2, be2, hA);

    // 4 GCN layers: hB = hA @ Wg[l];  hA = relu(agg(hB) + self + bias)
    for (int l = 0; l < NLAYERS; ++l) {
        k_gemm<<<gemm_grid, 256, 0, stream>>>(hA, Wg + (size_t)l * HID * HID, hB);
        k_agg<<<(N_NODES + 3) / 4, 256, 0, stream>>>(hB, erec, offs, dinv,
                                                     bg + (size_t)l * HID, hA);
    }

    // pooling + output head
    k_pool<<<(N_NODES + 8 * PN - 1) / (8 * PN), 256, 0, stream>>>(hA, bidx, pooled, cnt);
    k_out<<<NGRAPH, HID, 0, stream>>>(pooled, cnt, Wo, bo, out);
}

// Round 5
// 579.784 us; speedup vs baseline: 1.0381x; 1.0381x over previous
//
#include <hip/hip_runtime.h>

#define N_NODES 50000
#define N_EDGES 800000
#define FEAT    16
#define HID     128
#define NLAYERS 4
#define OUTD    12
#define NGRAPH  1024
#define SCAN_NB 196   // ceil((N_NODES+1)/256)

__device__ inline float4 f4zero() { return make_float4(0.f, 0.f, 0.f, 0.f); }
__device__ inline float4 f4fma(float a, float4 w, float4 acc) {
    acc.x = fmaf(a, w.x, acc.x);
    acc.y = fmaf(a, w.y, acc.y);
    acc.z = fmaf(a, w.z, acc.z);
    acc.w = fmaf(a, w.w, acc.w);
    return acc;
}
__device__ inline float4 f4add(float4 a, float4 b) {
    return make_float4(a.x + b.x, a.y + b.y, a.z + b.z, a.w + b.w);
}
__device__ inline float4 f4relu(float4 a) {
    return make_float4(fmaxf(a.x, 0.f), fmaxf(a.y, 0.f), fmaxf(a.z, 0.f), fmaxf(a.w, 0.f));
}

// ---------------- degree / dinv ----------------
__global__ void k_deg(const int* __restrict__ ei, int* __restrict__ degi) {
    int e = blockIdx.x * 256 + threadIdx.x;
    if (e < N_EDGES) atomicAdd(&degi[ei[N_EDGES + e]], 1);
}

__global__ void k_dinv(const int* __restrict__ degi, float* __restrict__ dinv) {
    int i = blockIdx.x * 256 + threadIdx.x;
    if (i < N_NODES) dinv[i] = rsqrtf((float)degi[i] + 1.0f);
}

// ---------------- 3-kernel exclusive scan over deg (N_NODES+1 elems) ----------------
__global__ void k_scan_part(const int* __restrict__ degi, int* __restrict__ part) {
    __shared__ int s[256];
    int t = threadIdx.x;
    int i = blockIdx.x * 256 + t;
    int v = (i < N_NODES) ? degi[i] : 0;
    s[t] = v;
    __syncthreads();
    for (int st = 128; st > 0; st >>= 1) {
        if (t < st) s[t] += s[t + st];
        __syncthreads();
    }
    if (t == 0) part[blockIdx.x] = s[0];
}

__global__ void k_scan_mid(int* __restrict__ part) {
    __shared__ int s[256];
    int t = threadIdx.x;
    int v = (t < SCAN_NB) ? part[t] : 0;
    s[t] = v;
    __syncthreads();
    for (int st = 1; st < 256; st <<= 1) {
        int u = (t >= st) ? s[t - st] : 0;
        __syncthreads();
        s[t] += u;
        __syncthreads();
    }
    if (t < SCAN_NB) part[t] = s[t] - v;   // exclusive
}

__global__ void k_scan_final(const int* __restrict__ degi, const int* __restrict__ part,
                             int* __restrict__ offs) {
    __shared__ int s[256];
    int t = threadIdx.x;
    int i = blockIdx.x * 256 + t;
    int v = (i < N_NODES) ? degi[i] : 0;
    s[t] = v;
    __syncthreads();
    for (int st = 1; st < 256; st <<= 1) {
        int u = (t >= st) ? s[t - st] : 0;
        __syncthreads();
        s[t] += u;
        __syncthreads();
    }
    if (i <= N_NODES) offs[i] = s[t] - v + part[blockIdx.x];
}

// ---------------- CSR fill: packed record {src, dinv[src]} ----------------
__global__ void k_fill(const int* __restrict__ ei, const int* __restrict__ offs,
                       const float* __restrict__ dinv,
                       int* __restrict__ cursor, int2* __restrict__ erec) {
    int e = blockIdx.x * 256 + threadIdx.x;
    if (e < N_EDGES) {
        int srcv = ei[e];
        int dstv = ei[N_EDGES + e];
        int p = atomicAdd(&cursor[dstv], 1);
        erec[offs[dstv] + p] = make_int2(srcv, __float_as_int(dinv[srcv]));
    }
}

// ---------------- fused node-embed MLP: hA = relu(x@We1+be1)@We2+be2 ----------------
#define GM 64
__global__ void __launch_bounds__(256) k_embed_fused(
        const float* __restrict__ x,
        const float* __restrict__ W1, const float* __restrict__ b1,
        const float* __restrict__ W2, const float* __restrict__ b2,
        float* __restrict__ outp) {
    __shared__ float x_l[GM][FEAT];
    __shared__ float a_l[GM][HID];
    int t = threadIdx.x;
    long n0 = (long)blockIdx.x * GM;
    // coop load 64x16 floats = 256 float4, 1/thread
    {
        int r  = t >> 2;
        int c4 = (t & 3) << 2;
        long n = n0 + r;
        float4 v = (n < N_NODES) ? *(const float4*)&x[n * FEAT + c4] : f4zero();
        *(float4*)&x_l[r][c4] = v;
    }
    __syncthreads();
    int fgrp = t & 31, ngrp = t >> 5;
    int f4 = fgrp << 2;
    // stage 1: t = relu(x@W1+b1), K=16
    {
        float4 acc[8];
#pragma unroll
        for (int r = 0; r < 8; ++r) acc[r] = f4zero();
#pragma unroll
        for (int k4 = 0; k4 < 4; ++k4) {
            float4 wv[4];
#pragma unroll
            for (int kk = 0; kk < 4; ++kk)
                wv[kk] = *(const float4*)&W1[(k4 * 4 + kk) * HID + f4];
            float4 xv[8];
#pragma unroll
            for (int r = 0; r < 8; ++r)
                xv[r] = *(const float4*)&x_l[ngrp * 8 + r][k4 << 2];
#pragma unroll
            for (int r = 0; r < 8; ++r) {
                acc[r] = f4fma(xv[r].x, wv[0], acc[r]);
                acc[r] = f4fma(xv[r].y, wv[1], acc[r]);
                acc[r] = f4fma(xv[r].z, wv[2], acc[r]);
                acc[r] = f4fma(xv[r].w, wv[3], acc[r]);
            }
        }
        float4 bv = *(const float4*)&b1[f4];
#pragma unroll
        for (int r = 0; r < 8; ++r)
            *(float4*)&a_l[ngrp * 8 + r][f4] = f4relu(f4add(acc[r], bv));
    }
    __syncthreads();
    // stage 2: out = t @ W2 + b2, K=128
    float4 acc[8];
#pragma unroll
    for (int r = 0; r < 8; ++r) acc[r] = f4zero();
#pragma unroll 4
    for (int k4 = 0; k4 < 32; ++k4) {
        float4 wv[4];
#pragma unroll
        for (int kk = 0; kk < 4; ++kk)
            wv[kk] = *(const float4*)&W2[(k4 * 4 + kk) * HID + f4];
        float4 av[8];
#pragma unroll
        for (int r = 0; r < 8; ++r)
            av[r] = *(const float4*)&a_l[ngrp * 8 + r][k4 << 2];
#pragma unroll
        for (int r = 0; r < 8; ++r) {
            acc[r] = f4fma(av[r].x, wv[0], acc[r]);
            acc[r] = f4fma(av[r].y, wv[1], acc[r]);
            acc[r] = f4fma(av[r].z, wv[2], acc[r]);
            acc[r] = f4fma(av[r].w, wv[3], acc[r]);
        }
    }
    float4 bv = *(const float4*)&b2[f4];
#pragma unroll
    for (int r = 0; r < 8; ++r) {
        long n = n0 + ngrp * 8 + r;
        if (n < N_NODES) *(float4*)&outp[n * HID + f4] = f4add(acc[r], bv);
    }
}

// ---------------- fused GCN layer: hout = relu( agg(h) @ W + b ) ----------------
// Uses agg/GEMM commutativity: agg(h @ W) == agg(h) @ W (both linear in h).
// Phase A: each wave aggregates 16 dst nodes (gather h rows via CSR) into LDS.
// Phase B: M=64 GEMM from LDS with bias+relu epilogue.
__global__ void __launch_bounds__(256) k_layer(
        const float* __restrict__ h,
        const int2* __restrict__ erec, const int* __restrict__ offs,
        const float* __restrict__ dinv,
        const float* __restrict__ W, const float* __restrict__ bias,
        float* __restrict__ hout) {
    __shared__ float a_l[GM][HID];
    int t = threadIdx.x;
    int lane = t & 63;
    int w = t >> 6;                       // wave 0..3
    long n0 = (long)blockIdx.x * GM;
    const float2* h2 = (const float2*)h;

    // ---- Phase A: aggregation into LDS ----
    for (int rep = 0; rep < 16; ++rep) {
        int row = w * 16 + rep;
        long i = n0 + row;
        float ax = 0.f, ay = 0.f;
        if (i < N_NODES) {
            float di = dinv[i];
            int s0 = offs[i], s1 = offs[i + 1];
            float2 self = h2[i * 64 + lane];
            ax = di * di * self.x;
            ay = di * di * self.y;
            for (int base = s0; base < s1; base += 64) {
                int n = s1 - base; if (n > 64) n = 64;
                int last = n - 1;
                int2 e = (lane < n) ? erec[base + lane] : make_int2(0, 0);
                int   sv_l = e.x;
                float nm_l = __int_as_float(e.y);
                for (int k = 0; k < n; k += 8) {
                    int a[8]; float m[8];
#pragma unroll
                    for (int u = 0; u < 8; ++u) {
                        int kk = k + u;
                        int ks = kk < last ? kk : last;   // clamp to last real edge
                        a[u] = __shfl(sv_l, ks);
                        float mu = __shfl(nm_l, ks);
                        m[u] = (kk < n) ? mu * di : 0.f;
                    }
                    float2 v[8];
#pragma unroll
                    for (int u = 0; u < 8; ++u) v[u] = h2[(long)a[u] * 64 + lane];
#pragma unroll
                    for (int u = 0; u < 8; ++u) {
                        ax = fmaf(m[u], v[u].x, ax);
                        ay = fmaf(m[u], v[u].y, ay);
                    }
                }
            }
        }
        *(float2*)&a_l[row][lane << 1] = make_float2(ax, ay);
    }
    __syncthreads();

    // ---- Phase B: GEMM from LDS + bias + relu ----
    int fgrp = t & 31, ngrp = t >> 5;
    int f4 = fgrp << 2;
    float4 acc[8];
#pragma unroll
    for (int r = 0; r < 8; ++r) acc[r] = f4zero();
#pragma unroll 4
    for (int k4 = 0; k4 < 32; ++k4) {
        float4 wv[4];
#pragma unroll
        for (int kk = 0; kk < 4; ++kk)
            wv[kk] = *(const float4*)&W[(k4 * 4 + kk) * HID + f4];
        float4 av[8];
#pragma unroll
        for (int r = 0; r < 8; ++r)
            av[r] = *(const float4*)&a_l[ngrp * 8 + r][k4 << 2];
#pragma unroll
        for (int r = 0; r < 8; ++r) {
            acc[r] = f4fma(av[r].x, wv[0], acc[r]);
            acc[r] = f4fma(av[r].y, wv[1], acc[r]);
            acc[r] = f4fma(av[r].z, wv[2], acc[r]);
            acc[r] = f4fma(av[r].w, wv[3], acc[r]);
        }
    }
    float4 bv = *(const float4*)&bias[f4];
#pragma unroll
    for (int r = 0; r < 8; ++r) {
        long n = n0 + ngrp * 8 + r;
        if (n < N_NODES) *(float4*)&hout[n * HID + f4] = f4relu(f4add(acc[r], bv));
    }
}

// ---------------- pooling: sorted-batch run-length accumulation ----------------
#define PN 16
__global__ void __launch_bounds__(256) k_pool(
        const float* __restrict__ h, const int* __restrict__ batch,
        float* __restrict__ pooled, float* __restrict__ cnt) {
    int t = threadIdx.x;
    int lane = t & 31, grp = t >> 5;
    long n0 = ((long)blockIdx.x * 8 + grp) * PN;
    if (n0 >= N_NODES) return;
    long n1 = n0 + PN; if (n1 > N_NODES) n1 = N_NODES;
    const float4* h4 = (const float4*)h;
    float4 run = f4zero();
    int curg = batch[n0];
    int c = 0;
    for (long n = n0; n < n1; ++n) {
        int g = batch[n];
        if (g != curg) {
            float* pb = &pooled[(long)curg * HID + (lane << 2)];
            atomicAdd(pb + 0, run.x); atomicAdd(pb + 1, run.y);
            atomicAdd(pb + 2, run.z); atomicAdd(pb + 3, run.w);
            if (lane == 0) atomicAdd(&cnt[curg], (float)c);
            run = f4zero(); c = 0; curg = g;
        }
        run = f4add(run, h4[n * 32 + lane]);
        ++c;
    }
    float* pb = &pooled[(long)curg * HID + (lane << 2)];
    atomicAdd(pb + 0, run.x); atomicAdd(pb + 1, run.y);
    atomicAdd(pb + 2, run.z); atomicAdd(pb + 3, run.w);
    if (lane == 0) atomicAdd(&cnt[curg], (float)c);
}

// ---------------- output head: out = (pooled/cnt) @ Wo + bo ----------------
__global__ void __launch_bounds__(HID) k_out(
        const float* __restrict__ pooled, const float* __restrict__ cnt,
        const float* __restrict__ Wo, const float* __restrict__ bo,
        float* __restrict__ out) {
    __shared__ float p[HID];
    int g = blockIdx.x;
    int f = threadIdx.x;
    float inv = 1.0f / fmaxf(cnt[g], 1.0f);
    p[f] = pooled[g * HID + f] * inv;
    __syncthreads();
    if (f < OUTD) {
        float acc = bo[f];
#pragma unroll 8
        for (int k = 0; k < HID; ++k) acc += p[k] * Wo[k * OUTD + f];
        out[g * OUTD + f] = acc;
    }
}

extern "C" void kernel_launch(void* const* d_in, const int* in_sizes, int n_in,
                              void* d_out, int out_size, void* d_ws, size_t ws_size,
                              hipStream_t stream) {
    const float* x    = (const float*)d_in[0];
    const int*   ei   = (const int*)d_in[1];
    // d_in[2] edge_attr unused
    const int*   bidx = (const int*)d_in[3];
    const float* We1  = (const float*)d_in[4];
    const float* be1  = (const float*)d_in[5];
    const float* We2  = (const float*)d_in[6];
    const float* be2  = (const float*)d_in[7];
    const float* Wg   = (const float*)d_in[8];
    const float* bg   = (const float*)d_in[9];
    const float* Wo   = (const float*)d_in[10];
    const float* bo   = (const float*)d_in[11];
    float* out = (float*)d_out;

    // ---- workspace layout (256B aligned) ----
    char* ws = (char*)d_ws;
    size_t o = 0;
    auto take = [&](size_t bytes) { size_t r = o; o += (bytes + 255) & ~(size_t)255; return r; };
    size_t off_degi   = take((size_t)N_NODES * 4);
    size_t off_cursor = take((size_t)N_NODES * 4);
    size_t off_pooled = take((size_t)NGRAPH * HID * 4);
    size_t off_cnt    = take((size_t)NGRAPH * 4);
    size_t zero_bytes = o;                       // [0, o) gets memset to 0
    size_t off_dinv   = take((size_t)N_NODES * 4);
    size_t off_offs   = take((size_t)(N_NODES + 1) * 4);
    size_t off_part   = take((size_t)256 * 4);
    size_t off_erec   = take((size_t)N_EDGES * 8);
    size_t off_hA     = take((size_t)N_NODES * HID * 4);
    size_t off_hB     = take((size_t)N_NODES * HID * 4);

    int*   degi   = (int*)(ws + off_degi);
    int*   cursor = (int*)(ws + off_cursor);
    float* pooled = (float*)(ws + off_pooled);
    float* cnt    = (float*)(ws + off_cnt);
    float* dinv   = (float*)(ws + off_dinv);
    int*   offs   = (int*)(ws + off_offs);
    int*   part   = (int*)(ws + off_part);
    int2*  erec   = (int2*)(ws + off_erec);
    float* hA     = (float*)(ws + off_hA);
    float* hB     = (float*)(ws + off_hB);

    hipMemsetAsync(d_ws, 0, zero_bytes, stream);

    // degree + dinv + CSR build (amortized across 4 layers)
    k_deg<<<(N_EDGES + 255) / 256, 256, 0, stream>>>(ei, degi);
    k_dinv<<<(N_NODES + 255) / 256, 256, 0, stream>>>(degi, dinv);
    k_scan_part<<<SCAN_NB, 256, 0, stream>>>(degi, part);
    k_scan_mid<<<1, 256, 0, stream>>>(part);
    k_scan_final<<<SCAN_NB, 256, 0, stream>>>(degi, part, offs);
    k_fill<<<(N_EDGES + 255) / 256, 256, 0, stream>>>(ei, offs, dinv, cursor, erec);

    // fused node-embed MLP
    int tile_grid = (N_NODES + GM - 1) / GM;
    k_embed_fused<<<tile_grid, 256, 0, stream>>>(x, We1, be1, We2, be2, hA);

    // 4 fused GCN layers: h <- relu( agg(h) @ Wg[l] + bg[l] )   (ping-pong hA/hB)
    float* hin = hA;
    float* hout2 = hB;
    for (int l = 0; l < NLAYERS; ++l) {
        k_layer<<<tile_grid, 256, 0, stream>>>(hin, erec, offs, dinv,
                                               Wg + (size_t)l * HID * HID,
                                               bg + (size_t)l * HID, hout2);
        float* tmp = hin; hin = hout2; hout2 = tmp;
    }

    // pooling + output head (final features in hin)
    k_pool<<<(N_NODES + 8 * PN - 1) / (8 * PN), 256, 0, stream>>>(hin, bidx, pooled, cnt);
    k_out<<<NGRAPH, HID, 0, stream>>>(pooled, cnt, Wo, bo, out);
}